// Round 1
// baseline (6692.426 us; speedup 1.0000x reference)
//
#include <hip/hip_runtime.h>
#include <float.h>

#define NS 1536
#define DD 64

// ws layout (float elements)
static const size_t OFF_A  = 0;                          // A = h_sat + b1: [1536][64]
static const size_t OFF_C2 = 98304;                      // C2 = h_uav transposed [16][1536][4]
static const size_t OFF_L  = 196608;                     // logits [1536][1536]
static const size_t OFF_TI = 196608 + (size_t)NS * NS;   // int top_idx [1536][64]
static const size_t OFF_TC = OFF_TI + (size_t)NS * 64;   // int top_cnt [1536]
static const size_t OFF_AS = OFF_TC + NS;                // int assign [1536]

// ---------------- Kernel A: first-layer projections ----------------
// A[i][d] = sum_k sat[i][k]*W1[k][d] + b1[d]
// C2[d>>2][j][d&3] = sum_k uav[j][k]*W1[64+k][d]   (layout for coalesced float4 in kB)
__global__ __launch_bounds__(64) void kA(const float* __restrict__ sat,
                                         const float* __restrict__ uav,
                                         const float* __restrict__ W1,
                                         const float* __restrict__ b1,
                                         float* __restrict__ A,
                                         float* __restrict__ C2) {
    const int row = blockIdx.x;
    const int d = threadIdx.x;
    float accA = b1[d];
    float accC = 0.f;
    const float* __restrict__ satr = sat + row * DD;
    const float* __restrict__ uavr = uav + row * DD;
#pragma unroll 8
    for (int k = 0; k < DD; ++k) {
        accA = fmaf(satr[k], W1[k * DD + d], accA);
        accC = fmaf(uavr[k], W1[(DD + k) * DD + d], accC);
    }
    A[row * DD + d] = accA;
    C2[((size_t)(d >> 2) * NS + row) * 4 + (d & 3)] = accC;
}

// ---------------- Kernel B: all-pairs logits ----------------
// Per wave: one i, 256 j (4 per lane). W2/A/b2/W3 are wave-uniform -> s_loads,
// FMAs use SGPR operand. C streamed as coalesced float4 (L2-resident).
__global__ __launch_bounds__(256) void kB(const float* __restrict__ A,
                                          const float* __restrict__ C2,
                                          const float* __restrict__ W2,
                                          const float* __restrict__ b2,
                                          const float* __restrict__ W3,
                                          float* __restrict__ L) {
    const int lane = threadIdx.x & 63;
    const int wave = threadIdx.x >> 6;
    const int i = __builtin_amdgcn_readfirstlane(blockIdx.x * 4 + wave);
    const int jbase = blockIdx.y * 256;
    const float* __restrict__ Ar = A + (size_t)i * DD;

    float u[4][32];
#pragma unroll
    for (int o = 0; o < 32; ++o) {
        const float b = b2[o];
        u[0][o] = b; u[1][o] = b; u[2][o] = b; u[3][o] = b;
    }

    const float4* __restrict__ C2v = (const float4*)C2;

    for (int d4 = 0; d4 < 16; ++d4) {
        float c[4][4];
#pragma unroll
        for (int p = 0; p < 4; ++p) {
            const float4 t = C2v[(size_t)d4 * NS + jbase + p * 64 + lane];
            c[p][0] = t.x; c[p][1] = t.y; c[p][2] = t.z; c[p][3] = t.w;
        }
#pragma unroll
        for (int dd = 0; dd < 4; ++dd) {
            const float a = Ar[d4 * 4 + dd];
            const float v0 = fmaxf(a + c[0][dd], 0.f);
            const float v1 = fmaxf(a + c[1][dd], 0.f);
            const float v2 = fmaxf(a + c[2][dd], 0.f);
            const float v3 = fmaxf(a + c[3][dd], 0.f);
            const float* __restrict__ w2r = W2 + (d4 * 4 + dd) * 32;
#pragma unroll
            for (int o = 0; o < 32; ++o) {
                const float w = w2r[o];
                u[0][o] = fmaf(v0, w, u[0][o]);
                u[1][o] = fmaf(v1, w, u[1][o]);
                u[2][o] = fmaf(v2, w, u[2][o]);
                u[3][o] = fmaf(v3, w, u[3][o]);
            }
        }
    }

#pragma unroll
    for (int p = 0; p < 4; ++p) {
        float acc = 0.f;
#pragma unroll
        for (int o = 0; o < 32; ++o)
            acc = fmaf(fmaxf(u[p][o], 0.f), W3[o], acc);
        L[(size_t)i * NS + jbase + p * 64 + lane] = acc;
    }
}

// ---------------- Kernel C: per-row sorted top-64 candidates ----------------
// Byte-histogram prefilter (monotone float->uint map), collect <=512 candidates,
// O(m^2) rank (val desc, idx asc to match numpy argmax first-max tie-break).
__global__ __launch_bounds__(256) void kC(const float* __restrict__ L,
                                          int* __restrict__ top_idx,
                                          int* __restrict__ top_cnt) {
    __shared__ int hist[256];
    __shared__ int suff[256];
    __shared__ float cv[512];
    __shared__ int ci[512];
    __shared__ int s_cnt;
    __shared__ int s_B;
    const int t = threadIdx.x;
    const int row = blockIdx.x;
    const float* __restrict__ Lr = L + (size_t)row * NS;

    hist[t] = 0;
    if (t == 0) s_cnt = 0;
    __syncthreads();

    unsigned ub[6]; float fv[6];
#pragma unroll
    for (int k = 0; k < 6; ++k) {
        const float x = Lr[t + 256 * k];
        fv[k] = x;
        unsigned b = __float_as_uint(x);
        b = (b & 0x80000000u) ? ~b : (b | 0x80000000u);
        ub[k] = b;
        atomicAdd(&hist[b >> 24], 1);
    }
    __syncthreads();

    suff[t] = hist[t];
    __syncthreads();
    for (int off = 1; off < 256; off <<= 1) {
        const int v = (t + off < 256) ? suff[t + off] : 0;
        __syncthreads();
        suff[t] += v;
        __syncthreads();
    }
    if (suff[t] >= 64 && (t == 255 || suff[t + 1] < 64)) s_B = t;
    __syncthreads();
    const int B = s_B;
    const int m = suff[B];
    if (m > 512) {          // degenerate row: kD will full-fallback it
        if (t == 0) top_cnt[row] = 0;
        return;
    }
#pragma unroll
    for (int k = 0; k < 6; ++k) {
        if ((ub[k] >> 24) >= (unsigned)B) {
            const int pos = atomicAdd(&s_cnt, 1);
            cv[pos] = fv[k];
            ci[pos] = t + 256 * k;
        }
    }
    __syncthreads();

    for (int e = t; e < m; e += 256) {
        const float v = cv[e]; const int id = ci[e];
        int r = 0;
        for (int s2 = 0; s2 < m; ++s2) {
            const float vs = cv[s2]; const int is2 = ci[s2];
            if (vs > v || (vs == v && is2 < id)) ++r;
        }
        if (r < 64) top_idx[row * 64 + r] = id;
    }
    if (t == 0) top_cnt[row] = 64;
}

// ---------------- Kernel D: sequential greedy (single wave) ----------------
__global__ __launch_bounds__(64) void kD(const float* __restrict__ L,
                                         const int* __restrict__ top_idx,
                                         const int* __restrict__ top_cnt,
                                         int* __restrict__ assign) {
    __shared__ int used_s[NS];
    volatile int* used = used_s;
    const int lane = threadIdx.x;
    for (int k = lane; k < NS; k += 64) used_s[k] = 0;
    __syncthreads();

    int cur[16], ccnt[16];
#pragma unroll
    for (int q = 0; q < 16; ++q) {
        cur[q] = top_idx[q * 64 + lane];
        ccnt[q] = top_cnt[q];
    }
    int jprev = -1;
    int a_pend = 0;  // used[] is all-zero before first pick

    for (int g = 0; g < NS; g += 16) {
        int nxt[16], ncnt[16];
        const bool have_next = (g + 16 < NS);
        if (have_next) {
#pragma unroll
            for (int q = 0; q < 16; ++q) {
                nxt[q] = top_idx[(g + 16 + q) * 64 + lane];
                ncnt[q] = top_cnt[g + 16 + q];
            }
        }
#pragma unroll
        for (int q = 0; q < 16; ++q) {
            const int i = g + q;
            const int c = cur[q];
            const int a = a_pend;
            // issue next row's used-read one iteration ahead (stale by at most
            // this iteration's pick; corrected via c != jprev next time)
            int cn = (q < 15) ? cur[q + 1] : (have_next ? nxt[0] : 0);
            cn = ((unsigned)cn < (unsigned)NS) ? cn : 0;
            a_pend = used[cn];

            int j;
            const bool avail = (ccnt[q] != 0) && ((unsigned)c < (unsigned)NS) &&
                               (a == 0) && (c != jprev);
            const unsigned long long b = __ballot(avail);
            if (b) {
                const int f = __ffsll((unsigned long long)b) - 1;
                j = __shfl(c, f);
            } else {
                // full masked argmax over row i (always correct)
                const float* __restrict__ Lr = L + (size_t)i * NS;
                float bv = -FLT_MAX; int bi = NS;
                for (int k = 0; k < 24; ++k) {
                    const int col = lane + 64 * k;
                    const float v = Lr[col];
                    if (used[col] == 0) {
                        if (v > bv || (v == bv && col < bi)) { bv = v; bi = col; }
                    }
                }
#pragma unroll
                for (int o = 32; o >= 1; o >>= 1) {
                    const float ov = __shfl_xor(bv, o);
                    const int oi = __shfl_xor(bi, o);
                    if (ov > bv || (ov == bv && oi < bi)) { bv = ov; bi = oi; }
                }
                j = bi;
            }
            if (lane == 0) { used[j] = 1; assign[i] = j; }
            jprev = j;
        }
        if (have_next) {
#pragma unroll
            for (int q = 0; q < 16; ++q) { cur[q] = nxt[q]; ccnt[q] = ncnt[q]; }
        }
    }
}

// ---------------- Kernel E: emit [1536][2][64] output ----------------
__global__ __launch_bounds__(128) void kE(const float* __restrict__ sat,
                                          const float* __restrict__ uav,
                                          const int* __restrict__ assign,
                                          float* __restrict__ out) {
    const int i = blockIdx.x;
    const int t = threadIdx.x;
    if (t < 64) out[(size_t)i * 128 + t] = sat[(size_t)i * DD + t];
    else        out[(size_t)i * 128 + t] = uav[(size_t)assign[i] * DD + (t - 64)];
}

extern "C" void kernel_launch(void* const* d_in, const int* in_sizes, int n_in,
                              void* d_out, int out_size, void* d_ws, size_t ws_size,
                              hipStream_t stream) {
    const float* sat = (const float*)d_in[0];
    const float* uav = (const float*)d_in[1];
    const float* W1  = (const float*)d_in[2];
    const float* b1  = (const float*)d_in[3];
    const float* W2  = (const float*)d_in[4];
    const float* b2  = (const float*)d_in[5];
    const float* W3  = (const float*)d_in[6];
    // d_in[7] = b3: unused — sigmoid(x + b3) is monotone in x, argmax unchanged.

    float* ws = (float*)d_ws;
    float* A   = ws + OFF_A;
    float* C2  = ws + OFF_C2;
    float* L   = ws + OFF_L;
    int* top_idx = (int*)(ws + OFF_TI);
    int* top_cnt = (int*)(ws + OFF_TC);
    int* assign  = (int*)(ws + OFF_AS);

    hipLaunchKernelGGL(kA, dim3(NS), dim3(64), 0, stream, sat, uav, W1, b1, A, C2);
    hipLaunchKernelGGL(kB, dim3(NS / 4, NS / 256), dim3(256), 0, stream,
                       A, C2, W2, b2, W3, L);
    hipLaunchKernelGGL(kC, dim3(NS), dim3(256), 0, stream, L, top_idx, top_cnt);
    hipLaunchKernelGGL(kD, dim3(1), dim3(64), 0, stream, L, top_idx, top_cnt, assign);
    hipLaunchKernelGGL(kE, dim3(NS), dim3(128), 0, stream, sat, uav, assign,
                       (float*)d_out);
}

// Round 2
// 1954.410 us; speedup vs baseline: 3.4243x; 3.4243x over previous
//
#include <hip/hip_runtime.h>
#include <float.h>

#define NS 1536
#define DD 64

// ws layout (float elements)
static const size_t OFF_A  = 0;                          // A = h_sat + b1: [1536][64]
static const size_t OFF_C2 = 98304;                      // C2 = h_uav transposed [16][1536][4]
static const size_t OFF_L  = 196608;                     // logits [1536][1536]
static const size_t OFF_AS = 196608 + (size_t)NS * NS;   // int assign [1536]
// top_idx (ushort, 1536*256 = 786432 B) ALIASES the A/C2 region (dead after kB).

// ---------------- Kernel A: first-layer projections ----------------
__global__ __launch_bounds__(64) void kA(const float* __restrict__ sat,
                                         const float* __restrict__ uav,
                                         const float* __restrict__ W1,
                                         const float* __restrict__ b1,
                                         float* __restrict__ A,
                                         float* __restrict__ C2) {
    const int row = blockIdx.x;
    const int d = threadIdx.x;
    float accA = b1[d];
    float accC = 0.f;
    const float* __restrict__ satr = sat + row * DD;
    const float* __restrict__ uavr = uav + row * DD;
#pragma unroll 8
    for (int k = 0; k < DD; ++k) {
        accA = fmaf(satr[k], W1[k * DD + d], accA);
        accC = fmaf(uavr[k], W1[(DD + k) * DD + d], accC);
    }
    A[row * DD + d] = accA;
    C2[((size_t)(d >> 2) * NS + row) * 4 + (d & 3)] = accC;
}

// ---------------- Kernel B: all-pairs logits ----------------
__global__ __launch_bounds__(256) void kB(const float* __restrict__ A,
                                          const float* __restrict__ C2,
                                          const float* __restrict__ W2,
                                          const float* __restrict__ b2,
                                          const float* __restrict__ W3,
                                          float* __restrict__ L) {
    const int lane = threadIdx.x & 63;
    const int wave = threadIdx.x >> 6;
    const int i = __builtin_amdgcn_readfirstlane(blockIdx.x * 4 + wave);
    const int jbase = blockIdx.y * 256;
    const float* __restrict__ Ar = A + (size_t)i * DD;

    float u[4][32];
#pragma unroll
    for (int o = 0; o < 32; ++o) {
        const float b = b2[o];
        u[0][o] = b; u[1][o] = b; u[2][o] = b; u[3][o] = b;
    }

    const float4* __restrict__ C2v = (const float4*)C2;

    for (int d4 = 0; d4 < 16; ++d4) {
        float c[4][4];
#pragma unroll
        for (int p = 0; p < 4; ++p) {
            const float4 t = C2v[(size_t)d4 * NS + jbase + p * 64 + lane];
            c[p][0] = t.x; c[p][1] = t.y; c[p][2] = t.z; c[p][3] = t.w;
        }
#pragma unroll
        for (int dd = 0; dd < 4; ++dd) {
            const float a = Ar[d4 * 4 + dd];
            const float v0 = fmaxf(a + c[0][dd], 0.f);
            const float v1 = fmaxf(a + c[1][dd], 0.f);
            const float v2 = fmaxf(a + c[2][dd], 0.f);
            const float v3 = fmaxf(a + c[3][dd], 0.f);
            const float* __restrict__ w2r = W2 + (d4 * 4 + dd) * 32;
#pragma unroll
            for (int o = 0; o < 32; ++o) {
                const float w = w2r[o];
                u[0][o] = fmaf(v0, w, u[0][o]);
                u[1][o] = fmaf(v1, w, u[1][o]);
                u[2][o] = fmaf(v2, w, u[2][o]);
                u[3][o] = fmaf(v3, w, u[3][o]);
            }
        }
    }

#pragma unroll
    for (int p = 0; p < 4; ++p) {
        float acc = 0.f;
#pragma unroll
        for (int o = 0; o < 32; ++o)
            acc = fmaf(fmaxf(u[p][o], 0.f), W3[o], acc);
        L[(size_t)i * NS + jbase + p * 64 + lane] = acc;
    }
}

// ---------------- Kernel C: per-row sorted top-256 via 16-bit radix ----------------
// 2-level byte-radix prefilter (monotone float->uint), collect <=1024 candidates,
// O(m^2) rank (val desc, idx asc == numpy argmax tie-break).
// Output layout: top[row*256 + lane*4 + g] holds rank (g*64 + lane), as ushort.
__global__ __launch_bounds__(256) void kC(const float* __restrict__ L,
                                          unsigned short* __restrict__ top) {
    __shared__ int hist[256];
    __shared__ int suff[256];
    __shared__ float cv[1024];
    __shared__ int ci[1024];
    __shared__ int s_cnt, s_B0, s_base, s_B1;
    const int t = threadIdx.x;
    const int row = blockIdx.x;
    const float* __restrict__ Lr = L + (size_t)row * NS;

    // pre-fill with sentinel (degenerate rows -> kD full-fallback)
    top[row * 256 + t] = 0xFFFFu;

    hist[t] = 0;
    if (t == 0) s_cnt = 0;
    __syncthreads();

    unsigned ub[6]; float fv[6];
#pragma unroll
    for (int k = 0; k < 6; ++k) {
        const float x = Lr[t + 256 * k];
        fv[k] = x;
        unsigned b = __float_as_uint(x);
        b = (b & 0x80000000u) ? ~b : (b | 0x80000000u);
        ub[k] = b;
        atomicAdd(&hist[b >> 24], 1);
    }
    __syncthreads();

    // suffix scan pass 1
    suff[t] = hist[t];
    __syncthreads();
    for (int off = 1; off < 256; off <<= 1) {
        const int v = (t + off < 256) ? suff[t + off] : 0;
        __syncthreads();
        suff[t] += v;
        __syncthreads();
    }
    if (suff[t] >= 256 && (t == 255 || suff[t + 1] < 256)) {
        s_B0 = t;
        s_base = (t == 255) ? 0 : suff[t + 1];
    }
    __syncthreads();
    const unsigned B0 = (unsigned)s_B0;
    const int base = s_base;

    // pass 2: histogram of byte1 within bucket B0
    hist[t] = 0;
    __syncthreads();
#pragma unroll
    for (int k = 0; k < 6; ++k)
        if ((ub[k] >> 24) == B0) atomicAdd(&hist[(ub[k] >> 16) & 255], 1);
    __syncthreads();
    suff[t] = hist[t];
    __syncthreads();
    for (int off = 1; off < 256; off <<= 1) {
        const int v = (t + off < 256) ? suff[t + off] : 0;
        __syncthreads();
        suff[t] += v;
        __syncthreads();
    }
    const int need = 256 - base;   // >= 1 by construction
    if (suff[t] >= need && (t == 255 || suff[t + 1] < need)) s_B1 = t;
    __syncthreads();
    const unsigned B1 = (unsigned)s_B1;
    const int m = base + suff[B1];
    if (m > 1024) return;   // degenerate: sentinels stand, kD full-fallback

    // collect
#pragma unroll
    for (int k = 0; k < 6; ++k) {
        const unsigned hi = ub[k] >> 24;
        const unsigned mid = (ub[k] >> 16) & 255u;
        if (hi > B0 || (hi == B0 && mid >= B1)) {
            const int pos = atomicAdd(&s_cnt, 1);
            cv[pos] = fv[k];
            ci[pos] = t + 256 * k;
        }
    }
    __syncthreads();

    // O(m^2) exact rank; keep top-256
    for (int e = t; e < m; e += 256) {
        const float v = cv[e]; const int id = ci[e];
        int r = 0;
        for (int s2 = 0; s2 < m; ++s2) {
            const float vs = cv[s2];
            if (vs > v || (vs == v && ci[s2] < id)) ++r;
        }
        if (r < 256) top[row * 256 + (r & 63) * 4 + (r >> 6)] = (unsigned short)id;
    }
}

// ---------------- Kernel D: sequential greedy (single wave) ----------------
// Per row: 4 candidates/lane (ranks lane, 64+lane, 128+lane, 192+lane).
// used-flags for row i+1 prefetched during row i (stale only w.r.t. this row's
// pick, corrected via c != jprev). Pick via ballot + s_ff1 + v_readlane — no
// LDS in the serial chain.
__global__ __launch_bounds__(64) void kD(const float* __restrict__ L,
                                         const unsigned short* __restrict__ top,
                                         int* __restrict__ assign) {
    __shared__ int used_s[NS];
    volatile int* used = used_s;
    const int lane = threadIdx.x;
    for (int k = lane; k < NS; k += 64) used_s[k] = 0;
    __syncthreads();

    const uint2* __restrict__ T = (const uint2*)top;   // T[row*64 + lane]
    uint2 pA = T[lane];          // row 0 candidates
    uint2 pB = T[64 + lane];     // row 1 candidates
    int f0 = 0, f1 = 0, f2 = 0, f3 = 0;   // row-0 flags: nothing used yet
    int jprev = -1;

    for (int i = 0; i < NS; ++i) {
        uint2 pC;
        if (i + 2 < NS) pC = T[(i + 2) * 64 + lane];
        else { pC.x = 0xFFFFFFFFu; pC.y = 0xFFFFFFFFu; }

        // prefetch flags for row i+1 (candidates in pB); not in this row's chain
        const int n0 = (int)(pB.x & 0xFFFFu), n1 = (int)(pB.x >> 16);
        const int n2 = (int)(pB.y & 0xFFFFu), n3 = (int)(pB.y >> 16);
        const int g0 = used[n0 < NS ? n0 : 0];
        const int g1 = used[n1 < NS ? n1 : 0];
        const int g2 = used[n2 < NS ? n2 : 0];
        const int g3 = used[n3 < NS ? n3 : 0];

        const int c0 = (int)(pA.x & 0xFFFFu), c1 = (int)(pA.x >> 16);
        const int c2 = (int)(pA.y & 0xFFFFu), c3 = (int)(pA.y >> 16);
        const bool a0 = (c0 < NS) && (f0 == 0) && (c0 != jprev);
        const bool a1 = (c1 < NS) && (f1 == 0) && (c1 != jprev);
        const bool a2 = (c2 < NS) && (f2 == 0) && (c2 != jprev);
        const bool a3 = (c3 < NS) && (f3 == 0) && (c3 != jprev);
        const unsigned long long b0 = __ballot(a0);
        const unsigned long long b1 = __ballot(a1);
        const unsigned long long b2 = __ballot(a2);
        const unsigned long long b3 = __ballot(a3);

        int j;
        if (b0)      j = __builtin_amdgcn_readlane(c0, __ffsll(b0) - 1);
        else if (b1) j = __builtin_amdgcn_readlane(c1, __ffsll(b1) - 1);
        else if (b2) j = __builtin_amdgcn_readlane(c2, __ffsll(b2) - 1);
        else if (b3) j = __builtin_amdgcn_readlane(c3, __ffsll(b3) - 1);
        else {
            // full masked argmax over row i — all loads independent (unrolled)
            const float* __restrict__ Lr = L + (size_t)i * NS;
            float v[24];
#pragma unroll
            for (int k = 0; k < 24; ++k) v[k] = Lr[lane + (k << 6)];
            int uf[24];
#pragma unroll
            for (int k = 0; k < 24; ++k) uf[k] = used[lane + (k << 6)];
            float bv = -FLT_MAX; int bi = NS;
#pragma unroll
            for (int k = 0; k < 24; ++k) {
                const int col = lane + (k << 6);
                if (uf[k] == 0 && (v[k] > bv || (v[k] == bv && col < bi))) {
                    bv = v[k]; bi = col;
                }
            }
#pragma unroll
            for (int o = 32; o >= 1; o >>= 1) {
                const float ov = __shfl_xor(bv, o);
                const int oi = __shfl_xor(bi, o);
                if (ov > bv || (ov == bv && oi < bi)) { bv = ov; bi = oi; }
            }
            j = bi;
        }
        if (lane == 0) { used[j] = 1; assign[i] = j; }
        jprev = j;
        pA = pB; pB = pC;
        f0 = g0; f1 = g1; f2 = g2; f3 = g3;
    }
}

// ---------------- Kernel E: emit [1536][2][64] output ----------------
__global__ __launch_bounds__(128) void kE(const float* __restrict__ sat,
                                          const float* __restrict__ uav,
                                          const int* __restrict__ assign,
                                          float* __restrict__ out) {
    const int i = blockIdx.x;
    const int t = threadIdx.x;
    if (t < 64) out[(size_t)i * 128 + t] = sat[(size_t)i * DD + t];
    else        out[(size_t)i * 128 + t] = uav[(size_t)assign[i] * DD + (t - 64)];
}

extern "C" void kernel_launch(void* const* d_in, const int* in_sizes, int n_in,
                              void* d_out, int out_size, void* d_ws, size_t ws_size,
                              hipStream_t stream) {
    const float* sat = (const float*)d_in[0];
    const float* uav = (const float*)d_in[1];
    const float* W1  = (const float*)d_in[2];
    const float* b1  = (const float*)d_in[3];
    const float* W2  = (const float*)d_in[4];
    const float* b2  = (const float*)d_in[5];
    const float* W3  = (const float*)d_in[6];
    // d_in[7] = b3: sigmoid(x+b3) monotone in x — argmax unchanged.

    float* ws = (float*)d_ws;
    float* A   = ws + OFF_A;
    float* C2  = ws + OFF_C2;
    float* L   = ws + OFF_L;
    int* assign = (int*)(ws + OFF_AS);
    unsigned short* top = (unsigned short*)(ws + OFF_A);  // aliases A/C2 (dead after kB)

    hipLaunchKernelGGL(kA, dim3(NS), dim3(64), 0, stream, sat, uav, W1, b1, A, C2);
    hipLaunchKernelGGL(kB, dim3(NS / 4, NS / 256), dim3(256), 0, stream,
                       A, C2, W2, b2, W3, L);
    hipLaunchKernelGGL(kC, dim3(NS), dim3(256), 0, stream, L, top);
    hipLaunchKernelGGL(kD, dim3(1), dim3(64), 0, stream, L, top, assign);
    hipLaunchKernelGGL(kE, dim3(NS), dim3(128), 0, stream, sat, uav, assign,
                       (float*)d_out);
}

// Round 3
// 1213.401 us; speedup vs baseline: 5.5154x; 1.6107x over previous
//
#include <hip/hip_runtime.h>
#include <float.h>

#define NS 1536
#define DD 64

// ws layout (float elements)
static const size_t OFF_A  = 0;                          // A = h_sat + b1: [1536][64]
static const size_t OFF_C2 = 98304;                      // C2 = h_uav transposed [16][1536][4]
static const size_t OFF_L  = 196608;                     // logits [1536][1536]
static const size_t OFF_AS = 196608 + (size_t)NS * NS;   // int assign [1536]
// top_idx (ushort, 1536*256 = 786432 B) ALIASES the A/C2 region (dead after kB).

// ---------------- Kernel A: first-layer projections ----------------
__global__ __launch_bounds__(64) void kA(const float* __restrict__ sat,
                                         const float* __restrict__ uav,
                                         const float* __restrict__ W1,
                                         const float* __restrict__ b1,
                                         float* __restrict__ A,
                                         float* __restrict__ C2) {
    const int row = blockIdx.x;
    const int d = threadIdx.x;
    float accA = b1[d];
    float accC = 0.f;
    const float* __restrict__ satr = sat + row * DD;
    const float* __restrict__ uavr = uav + row * DD;
#pragma unroll 8
    for (int k = 0; k < DD; ++k) {
        accA = fmaf(satr[k], W1[k * DD + d], accA);
        accC = fmaf(uavr[k], W1[(DD + k) * DD + d], accC);
    }
    A[row * DD + d] = accA;
    C2[((size_t)(d >> 2) * NS + row) * 4 + (d & 3)] = accC;
}

// ---------------- Kernel B: all-pairs logits ----------------
__global__ __launch_bounds__(256) void kB(const float* __restrict__ A,
                                          const float* __restrict__ C2,
                                          const float* __restrict__ W2,
                                          const float* __restrict__ b2,
                                          const float* __restrict__ W3,
                                          float* __restrict__ L) {
    const int lane = threadIdx.x & 63;
    const int wave = threadIdx.x >> 6;
    const int i = __builtin_amdgcn_readfirstlane(blockIdx.x * 4 + wave);
    const int jbase = blockIdx.y * 256;
    const float* __restrict__ Ar = A + (size_t)i * DD;

    float u[4][32];
#pragma unroll
    for (int o = 0; o < 32; ++o) {
        const float b = b2[o];
        u[0][o] = b; u[1][o] = b; u[2][o] = b; u[3][o] = b;
    }

    const float4* __restrict__ C2v = (const float4*)C2;

    for (int d4 = 0; d4 < 16; ++d4) {
        float c[4][4];
#pragma unroll
        for (int p = 0; p < 4; ++p) {
            const float4 t = C2v[(size_t)d4 * NS + jbase + p * 64 + lane];
            c[p][0] = t.x; c[p][1] = t.y; c[p][2] = t.z; c[p][3] = t.w;
        }
#pragma unroll
        for (int dd = 0; dd < 4; ++dd) {
            const float a = Ar[d4 * 4 + dd];
            const float v0 = fmaxf(a + c[0][dd], 0.f);
            const float v1 = fmaxf(a + c[1][dd], 0.f);
            const float v2 = fmaxf(a + c[2][dd], 0.f);
            const float v3 = fmaxf(a + c[3][dd], 0.f);
            const float* __restrict__ w2r = W2 + (d4 * 4 + dd) * 32;
#pragma unroll
            for (int o = 0; o < 32; ++o) {
                const float w = w2r[o];
                u[0][o] = fmaf(v0, w, u[0][o]);
                u[1][o] = fmaf(v1, w, u[1][o]);
                u[2][o] = fmaf(v2, w, u[2][o]);
                u[3][o] = fmaf(v3, w, u[3][o]);
            }
        }
    }

#pragma unroll
    for (int p = 0; p < 4; ++p) {
        float acc = 0.f;
#pragma unroll
        for (int o = 0; o < 32; ++o)
            acc = fmaf(fmaxf(u[p][o], 0.f), W3[o], acc);
        L[(size_t)i * NS + jbase + p * 64 + lane] = acc;
    }
}

// ---------------- Kernel C: per-row sorted top-256 via 16-bit radix ----------------
__global__ __launch_bounds__(256) void kC(const float* __restrict__ L,
                                          unsigned short* __restrict__ top) {
    __shared__ int hist[256];
    __shared__ int suff[256];
    __shared__ float cv[1024];
    __shared__ int ci[1024];
    __shared__ int s_cnt, s_B0, s_base, s_B1;
    const int t = threadIdx.x;
    const int row = blockIdx.x;
    const float* __restrict__ Lr = L + (size_t)row * NS;

    top[row * 256 + t] = 0xFFFFu;   // sentinel (degenerate rows -> kD full-fallback)

    hist[t] = 0;
    if (t == 0) s_cnt = 0;
    __syncthreads();

    unsigned ub[6]; float fv[6];
#pragma unroll
    for (int k = 0; k < 6; ++k) {
        const float x = Lr[t + 256 * k];
        fv[k] = x;
        unsigned b = __float_as_uint(x);
        b = (b & 0x80000000u) ? ~b : (b | 0x80000000u);
        ub[k] = b;
        atomicAdd(&hist[b >> 24], 1);
    }
    __syncthreads();

    suff[t] = hist[t];
    __syncthreads();
    for (int off = 1; off < 256; off <<= 1) {
        const int v = (t + off < 256) ? suff[t + off] : 0;
        __syncthreads();
        suff[t] += v;
        __syncthreads();
    }
    if (suff[t] >= 256 && (t == 255 || suff[t + 1] < 256)) {
        s_B0 = t;
        s_base = (t == 255) ? 0 : suff[t + 1];
    }
    __syncthreads();
    const unsigned B0 = (unsigned)s_B0;
    const int base = s_base;

    hist[t] = 0;
    __syncthreads();
#pragma unroll
    for (int k = 0; k < 6; ++k)
        if ((ub[k] >> 24) == B0) atomicAdd(&hist[(ub[k] >> 16) & 255], 1);
    __syncthreads();
    suff[t] = hist[t];
    __syncthreads();
    for (int off = 1; off < 256; off <<= 1) {
        const int v = (t + off < 256) ? suff[t + off] : 0;
        __syncthreads();
        suff[t] += v;
        __syncthreads();
    }
    const int need = 256 - base;
    if (suff[t] >= need && (t == 255 || suff[t + 1] < need)) s_B1 = t;
    __syncthreads();
    const unsigned B1 = (unsigned)s_B1;
    const int m = base + suff[B1];
    if (m > 1024) return;

#pragma unroll
    for (int k = 0; k < 6; ++k) {
        const unsigned hi = ub[k] >> 24;
        const unsigned mid = (ub[k] >> 16) & 255u;
        if (hi > B0 || (hi == B0 && mid >= B1)) {
            const int pos = atomicAdd(&s_cnt, 1);
            cv[pos] = fv[k];
            ci[pos] = t + 256 * k;
        }
    }
    __syncthreads();

    for (int e = t; e < m; e += 256) {
        const float v = cv[e]; const int id = ci[e];
        int r = 0;
        for (int s2 = 0; s2 < m; ++s2) {
            const float vs = cv[s2];
            if (vs > v || (vs == v && ci[s2] < id)) ++r;
        }
        if (r < 256) top[row * 256 + (r & 63) * 4 + (r >> 6)] = (unsigned short)id;
    }
}

// ---------------- Kernel D: sequential greedy (single wave) ----------------
// Deep-pipelined: 16-slot register buffer of candidate rows; 8 loads issued per
// 8-row group, consumed 2 groups later -> no per-row vmcnt stall. No global
// stores in the loop (assign buffered in LDS). used[] flags for row i+1
// prefetched during row i (stale-by-one corrected via c != jprev).
__global__ __launch_bounds__(64) void kD(const float* __restrict__ L,
                                         const unsigned short* __restrict__ top,
                                         int* __restrict__ assign) {
    __shared__ int used_s[NS];
    __shared__ int assign_s[NS];
    const int lane = threadIdx.x;
    for (int k = lane; k < NS; k += 64) used_s[k] = 0;
    __syncthreads();

    const uint2* __restrict__ T = (const uint2*)top;   // T[row*64 + lane]

    uint2 buf[16];           // rows g..g+15
#pragma unroll
    for (int k = 0; k < 16; ++k) buf[k] = T[k * 64 + lane];

    int f0 = 0, f1 = 0, f2 = 0, f3 = 0;   // row-0 flags: nothing used yet
    int jprev = -1;

    for (int g = 0; g < NS; g += 8) {
        // issue loads for rows g+16..g+23 (consumed 2 groups from now)
        uint2 nb[8];
#pragma unroll
        for (int k = 0; k < 8; ++k) {
            int r = g + 16 + k;
            r = (r < NS) ? r : (NS - 1);
            nb[k] = T[r * 64 + lane];
        }

#pragma unroll
        for (int q = 0; q < 8; ++q) {
            const int i = g + q;

            // prefetch used-flags for row i+1 (candidates resident in buf[q+1])
            const uint2 pn = buf[q + 1];
            const int n0 = (int)(pn.x & 0xFFFFu), n1 = (int)(pn.x >> 16);
            const int n2 = (int)(pn.y & 0xFFFFu), n3 = (int)(pn.y >> 16);
            const int g0 = used_s[n0 < NS ? n0 : 0];
            const int g1 = used_s[n1 < NS ? n1 : 0];
            const int g2 = used_s[n2 < NS ? n2 : 0];
            const int g3 = used_s[n3 < NS ? n3 : 0];

            const uint2 pc = buf[q];
            const int c0 = (int)(pc.x & 0xFFFFu), c1 = (int)(pc.x >> 16);
            const int c2 = (int)(pc.y & 0xFFFFu), c3 = (int)(pc.y >> 16);
            const bool a0 = (c0 < NS) && (f0 == 0) && (c0 != jprev);
            const bool a1 = (c1 < NS) && (f1 == 0) && (c1 != jprev);
            const bool a2 = (c2 < NS) && (f2 == 0) && (c2 != jprev);
            const bool a3 = (c3 < NS) && (f3 == 0) && (c3 != jprev);
            const unsigned long long b0 = __ballot(a0);
            const unsigned long long b1 = __ballot(a1);
            const unsigned long long b2 = __ballot(a2);
            const unsigned long long b3 = __ballot(a3);

            int j;
            if (b0)      j = __builtin_amdgcn_readlane(c0, __ffsll(b0) - 1);
            else if (b1) j = __builtin_amdgcn_readlane(c1, __ffsll(b1) - 1);
            else if (b2) j = __builtin_amdgcn_readlane(c2, __ffsll(b2) - 1);
            else if (b3) j = __builtin_amdgcn_readlane(c3, __ffsll(b3) - 1);
            else {
                // full masked argmax over row i — independent unrolled loads
                const float* __restrict__ Lr = L + (size_t)i * NS;
                float v[24];
#pragma unroll
                for (int k = 0; k < 24; ++k) v[k] = Lr[lane + (k << 6)];
                int uf[24];
#pragma unroll
                for (int k = 0; k < 24; ++k) uf[k] = used_s[lane + (k << 6)];
                float bv = -FLT_MAX; int bi = NS;
#pragma unroll
                for (int k = 0; k < 24; ++k) {
                    const int col = lane + (k << 6);
                    if (uf[k] == 0 && (v[k] > bv || (v[k] == bv && col < bi))) {
                        bv = v[k]; bi = col;
                    }
                }
#pragma unroll
                for (int o = 32; o >= 1; o >>= 1) {
                    const float ov = __shfl_xor(bv, o);
                    const int oi = __shfl_xor(bi, o);
                    if (ov > bv || (ov == bv && oi < bi)) { bv = ov; bi = oi; }
                }
                j = bi;
            }
            if (lane == 0) { used_s[j] = 1; assign_s[i] = j; }
            jprev = j;
            f0 = g0; f1 = g1; f2 = g2; f3 = g3;
        }

        // rotate: waits only for loads issued ~8 rows ago (fully landed)
#pragma unroll
        for (int k = 0; k < 8; ++k) buf[k] = buf[k + 8];
#pragma unroll
        for (int k = 0; k < 8; ++k) buf[k + 8] = nb[k];
    }

    for (int k = lane; k < NS; k += 64) assign[k] = assign_s[k];
}

// ---------------- Kernel E: emit [1536][2][64] output ----------------
__global__ __launch_bounds__(128) void kE(const float* __restrict__ sat,
                                          const float* __restrict__ uav,
                                          const int* __restrict__ assign,
                                          float* __restrict__ out) {
    const int i = blockIdx.x;
    const int t = threadIdx.x;
    if (t < 64) out[(size_t)i * 128 + t] = sat[(size_t)i * DD + t];
    else        out[(size_t)i * 128 + t] = uav[(size_t)assign[i] * DD + (t - 64)];
}

extern "C" void kernel_launch(void* const* d_in, const int* in_sizes, int n_in,
                              void* d_out, int out_size, void* d_ws, size_t ws_size,
                              hipStream_t stream) {
    const float* sat = (const float*)d_in[0];
    const float* uav = (const float*)d_in[1];
    const float* W1  = (const float*)d_in[2];
    const float* b1  = (const float*)d_in[3];
    const float* W2  = (const float*)d_in[4];
    const float* b2  = (const float*)d_in[5];
    const float* W3  = (const float*)d_in[6];
    // d_in[7] = b3: sigmoid(x+b3) monotone in x — argmax unchanged.

    float* ws = (float*)d_ws;
    float* A   = ws + OFF_A;
    float* C2  = ws + OFF_C2;
    float* L   = ws + OFF_L;
    int* assign = (int*)(ws + OFF_AS);
    unsigned short* top = (unsigned short*)(ws + OFF_A);  // aliases A/C2 (dead after kB)

    hipLaunchKernelGGL(kA, dim3(NS), dim3(64), 0, stream, sat, uav, W1, b1, A, C2);
    hipLaunchKernelGGL(kB, dim3(NS / 4, NS / 256), dim3(256), 0, stream,
                       A, C2, W2, b2, W3, L);
    hipLaunchKernelGGL(kC, dim3(NS), dim3(256), 0, stream, L, top);
    hipLaunchKernelGGL(kD, dim3(1), dim3(64), 0, stream, L, top, assign);
    hipLaunchKernelGGL(kE, dim3(NS), dim3(128), 0, stream, sat, uav, assign,
                       (float*)d_out);
}